// Round 9
// baseline (94.710 us; speedup 1.0000x reference)
//
#include <hip/hip_runtime.h>
#include <hip/hip_bf16.h>
#include <math.h>

// Problem constants (reference: BATCH=2048, D=256, TEMP=0.5)
#define NB      2048
#define TWO_N   4096
#define DIM     256
#define EPS     1e-12f
#define NTILES  32                            // 4096 / 128
#define NBLK    (NTILES * (NTILES + 1) / 2)   // 528 triangle tiles

typedef __attribute__((ext_vector_type(8))) short  bf16x8;   // 8 bf16 = 4 VGPRs
typedef __attribute__((ext_vector_type(4))) float  f32x4;    // MFMA C/D

// ---------------------------------------------------------------------------
// K1: one wave per PAIR r in [0,2048): L2-normalize emb_i[r] -> z[r] and
// emb_j[r] -> z[r+NB] (bf16), and write the fp32-exact positive dot
// pos[r] = <z_i, z_j>. Also zeroes den[4096] and the ticket counter.
// ---------------------------------------------------------------------------
__global__ __launch_bounds__(256) void nrm_kernel(
    const float* __restrict__ emb_i, const float* __restrict__ emb_j,
    __hip_bfloat16* __restrict__ zb, float* __restrict__ pos,
    float* __restrict__ den, unsigned* __restrict__ cnt)
{
    int t = threadIdx.x;
    int wave = t >> 6, lane = t & 63;
    int r = blockIdx.x * 4 + wave;              // pair index 0..2047
    float4 a = ((const float4*)(emb_i + (size_t)r * DIM))[lane];
    float4 b = ((const float4*)(emb_j + (size_t)r * DIM))[lane];
    float sa = a.x*a.x + a.y*a.y + a.z*a.z + a.w*a.w;
    float sb = b.x*b.x + b.y*b.y + b.z*b.z + b.w*b.w;
    float sd = a.x*b.x + a.y*b.y + a.z*b.z + a.w*b.w;
    #pragma unroll
    for (int off = 32; off >= 1; off >>= 1) {
        sa += __shfl_xor(sa, off, 64);
        sb += __shfl_xor(sb, off, 64);
        sd += __shfl_xor(sd, off, 64);
    }
    float si = 1.0f / fmaxf(sqrtf(sa), EPS);
    float sj = 1.0f / fmaxf(sqrtf(sb), EPS);

    union { __hip_bfloat16 h[4]; uint2 u; } pk;
    pk.h[0] = __float2bfloat16(a.x * si);
    pk.h[1] = __float2bfloat16(a.y * si);
    pk.h[2] = __float2bfloat16(a.z * si);
    pk.h[3] = __float2bfloat16(a.w * si);
    ((uint2*)(zb + (size_t)r * DIM))[lane] = pk.u;
    pk.h[0] = __float2bfloat16(b.x * sj);
    pk.h[1] = __float2bfloat16(b.y * sj);
    pk.h[2] = __float2bfloat16(b.z * sj);
    pk.h[3] = __float2bfloat16(b.w * sj);
    ((uint2*)(zb + (size_t)(r + NB) * DIM))[lane] = pk.u;

    if (lane == 0) pos[r] = sd * si * sj;
    if (t < 8) den[blockIdx.x * 8 + t] = 0.0f;  // 512 blocks x 8 = 4096
    if (blockIdx.x == 0 && t == 0) *cnt = 0u;
}

// ---------------------------------------------------------------------------
// K2: den[r] += sum_j exp(2 * z_r . z_j) via bf16 MFMA, symmetric: 1-D grid
// of exactly the 528 upper-triangle 128x128 tiles (id = by*(by+1)/2 + bx).
// Off-diagonal blocks scatter both row-sums and col-sums into den.
// 4 waves in 2x2; wave tile 64x64 = 4x4 MFMA 16x16x32 accumulators.
//
// K-loop: 4-deep register pipeline (fragments for steps k..k+3 in flight).
// Rationale (R8 post-mortem): occupancy is GRID-limited (528 blocks / 256 CU
// = ~2 blocks/CU, ~8 waves/CU), so VGPRs are free — launch_bounds(256,2)
// lifts the cap to 256 and the pipeline covers the ~200-cyc L2 latency with
// ~231 cyc of MFMA issue (3 steps x 77 cyc) instead of 77 (1 step).
//
// SYNC NOTE (R6+R7 post-mortems): NO fences anywhere.
//  - seq_cst __threadfence() per block  -> buffer_inv sc1 (L2 invalidate)
//    evicted z for running blocks: 62 us.
//  - release-agent builtin fence per block -> buffer_wbl2 sc1 (full L2
//    writeback walk) serialized block turnover: 48 us, WRITE_SIZE 2.6 MB.
// Correctness without fences: den/cnt adds are device-scope atomics
// (coherence-point-operating, nothing dirty in per-XCD L2), and
// __syncthreads() drains vmcnt(0) before its s_barrier, so each block's
// den-adds are performed-at-memory before its ticket add. The last block
// reads den with agent-scope atomic loads (coherence-point reads).
// ---------------------------------------------------------------------------
__global__ __launch_bounds__(256, 2) void simexp_kernel(
    const __hip_bfloat16* __restrict__ zb, const float* __restrict__ pos,
    float* __restrict__ den, unsigned* __restrict__ cnt,
    float* __restrict__ out)
{
    // Decode linear triangle index -> (bx, by), bx <= by.
    int id = blockIdx.x;
    int by = (int)((sqrtf(8.0f * (float)id + 1.0f) - 1.0f) * 0.5f);
    while ((by + 1) * (by + 2) / 2 <= id) ++by;   // fix float rounding
    while (by * (by + 1) / 2 > id) --by;
    int bx = id - by * (by + 1) / 2;

    const short* Z = (const short*)zb;
    int t = threadIdx.x;
    int w = t >> 6, lane = t & 63;
    int quad = lane >> 4, c16 = lane & 15;
    int wm = w >> 1, wn = w & 1;
    int rbase = bx * 128 + wm * 64;
    int jbase = by * 128 + wn * 64;

    const short* ap[4];
    const short* bp[4];
    #pragma unroll
    for (int mt = 0; mt < 4; ++mt)
        ap[mt] = Z + (size_t)(rbase + mt * 16 + c16) * DIM + quad * 8;
    #pragma unroll
    for (int nt = 0; nt < 4; ++nt)
        bp[nt] = Z + (size_t)(jbase + nt * 16 + c16) * DIM + quad * 8;

    f32x4 acc[4][4];
    #pragma unroll
    for (int mt = 0; mt < 4; ++mt)
        #pragma unroll
        for (int nt = 0; nt < 4; ++nt)
            acc[mt][nt] = (f32x4){0.f, 0.f, 0.f, 0.f};

    // 4-deep register pipeline: preload steps 0..2, then load kk+3 in-loop.
    bf16x8 af[4][4], bfv[4][4];
    #pragma unroll
    for (int s = 0; s < 3; ++s) {
        #pragma unroll
        for (int mt = 0; mt < 4; ++mt)
            af[s][mt] = *(const bf16x8*)(ap[mt] + s * 32);
        #pragma unroll
        for (int nt = 0; nt < 4; ++nt)
            bfv[s][nt] = *(const bf16x8*)(bp[nt] + s * 32);
    }

    #pragma unroll
    for (int kk = 0; kk < 8; ++kk) {
        int cur = kk & 3;
        if (kk + 3 < 8) {
            int pre = (kk + 3) & 3;
            #pragma unroll
            for (int mt = 0; mt < 4; ++mt)
                af[pre][mt] = *(const bf16x8*)(ap[mt] + (kk + 3) * 32);
            #pragma unroll
            for (int nt = 0; nt < 4; ++nt)
                bfv[pre][nt] = *(const bf16x8*)(bp[nt] + (kk + 3) * 32);
        }
        #pragma unroll
        for (int mt = 0; mt < 4; ++mt)
            #pragma unroll
            for (int nt = 0; nt < 4; ++nt)
                acc[mt][nt] = __builtin_amdgcn_mfma_f32_16x16x32_bf16(
                    af[cur][mt], bfv[cur][nt], acc[mt][nt], 0, 0, 0);
    }

    // Epilogue. Row of acc[mt][nt][rg] = rbase+mt*16+quad*4+rg,
    // col = jbase+nt*16+c16.
    float rsum[4][4];
    #pragma unroll
    for (int mt = 0; mt < 4; ++mt)
        #pragma unroll
        for (int rg = 0; rg < 4; ++rg) rsum[mt][rg] = 0.f;

    if (bx == by) {
        // Diagonal block: mask r==j, row-sums only.
        #pragma unroll
        for (int mt = 0; mt < 4; ++mt) {
            #pragma unroll
            for (int nt = 0; nt < 4; ++nt) {
                int j = jbase + nt * 16 + c16;
                #pragma unroll
                for (int rg = 0; rg < 4; ++rg) {
                    int r = rbase + mt * 16 + quad * 4 + rg;
                    float e = __expf(2.0f * acc[mt][nt][rg]);
                    rsum[mt][rg] += (r == j) ? 0.f : e;
                }
            }
        }
    } else {
        // Off-diagonal: no diagonal possible; row-sums AND col-sums.
        float csum[4] = {0.f, 0.f, 0.f, 0.f};
        #pragma unroll
        for (int mt = 0; mt < 4; ++mt) {
            #pragma unroll
            for (int nt = 0; nt < 4; ++nt) {
                #pragma unroll
                for (int rg = 0; rg < 4; ++rg) {
                    float e = __expf(2.0f * acc[mt][nt][rg]);
                    rsum[mt][rg] += e;
                    csum[nt] += e;
                }
            }
        }
        // col c16 of tile nt: sum the 4 quads, atomic from quad 0.
        #pragma unroll
        for (int nt = 0; nt < 4; ++nt) {
            float v = csum[nt];
            v += __shfl_xor(v, 16, 64);
            v += __shfl_xor(v, 32, 64);
            if (quad == 0)
                atomicAdd(&den[jbase + nt * 16 + c16], v);
        }
    }

    // Row-sums: reduce the 16 col-lanes of each quad, atomic from c16==0.
    #pragma unroll
    for (int mt = 0; mt < 4; ++mt) {
        #pragma unroll
        for (int rg = 0; rg < 4; ++rg) {
            float v = rsum[mt][rg];
            v += __shfl_xor(v, 1, 64);
            v += __shfl_xor(v, 2, 64);
            v += __shfl_xor(v, 4, 64);
            v += __shfl_xor(v, 8, 64);
            if (c16 == 0)
                atomicAdd(&den[rbase + mt * 16 + quad * 4 + rg], v);
        }
    }

    // ------------- last-block-done: final loss reduction -------------------
    // __syncthreads() drains vmcnt(0) -> this block's den atomics are
    // performed at the coherence point before the ticket add below.
    __shared__ bool last;
    __syncthreads();
    if (t == 0)
        last = (__hip_atomic_fetch_add(cnt, 1u, __ATOMIC_RELAXED,
                                       __HIP_MEMORY_SCOPE_AGENT) == NBLK - 1);
    __syncthreads();
    if (!last) return;

    __shared__ float red[4];
    float s = 0.f;
    for (int r = t; r < TWO_N; r += 256) {
        float d = __hip_atomic_load(&den[r], __ATOMIC_RELAXED,
                                    __HIP_MEMORY_SCOPE_AGENT);
        s += logf(d);
    }
    for (int p = t; p < NB; p += 256) s -= 4.0f * pos[p];
    #pragma unroll
    for (int off = 32; off >= 1; off >>= 1) s += __shfl_xor(s, off, 64);
    if ((t & 63) == 0) red[t >> 6] = s;
    __syncthreads();
    if (t == 0)
        out[0] = (red[0] + red[1] + red[2] + red[3]) * (1.0f / (float)TWO_N);
}

// ---------------------------------------------------------------------------
extern "C" void kernel_launch(void* const* d_in, const int* in_sizes, int n_in,
                              void* d_out, int out_size, void* d_ws, size_t ws_size,
                              hipStream_t stream)
{
    const float* emb_i = (const float*)d_in[0];
    const float* emb_j = (const float*)d_in[1];
    float* out = (float*)d_out;

    __hip_bfloat16* zb = (__hip_bfloat16*)d_ws;           // 4096*256 bf16 = 2 MB
    float* den = (float*)((char*)d_ws + (size_t)TWO_N * DIM * sizeof(__hip_bfloat16));
    float* pos = den + TWO_N;                             // 2048 f32
    unsigned* cnt = (unsigned*)(pos + NB);                // 1 u32 ticket

    nrm_kernel<<<NB / 4, 256, 0, stream>>>(emb_i, emb_j, zb, pos, den, cnt);

    simexp_kernel<<<NBLK, 256, 0, stream>>>(zb, pos, den, cnt, out);
}